// Round 21
// baseline (67.892 us; speedup 1.0000x reference)
//
#include <hip/hip_runtime.h>

typedef __attribute__((ext_vector_type(4))) int  i32x4;
typedef __attribute__((ext_vector_type(2))) float f32x2;

#define IC   256
#define OCH  128
#define BSZ  16
#define IH   64
#define IW   64
#define OH2  128
#define OW2  128
#define QMAXF 127.0f

// ws float-offset layout
#define WS_WSCALE 0        // 256 per-ic weight absmax
#define WS_APART  256      // 8*256 per-(bq,ic) act absmax partials
#define WS_F      2816     // sx*sw
#define WS_WQ8    3072     // int8 [9][16][128][16] quantized weights (294912 B)
#define WS_QX     76800    // int8 [16][64][64][256] pre-swizzled quantized x (16.78 MB)

// ---------------- K1: per-channel absmax (partials over batch) ----------------
__global__ __launch_bounds__(256) void k_channel_scales(
        const float* __restrict__ x, const float* __restrict__ w,
        float* __restrict__ ws) {
    const int ic = blockIdx.x;
    const int bq = blockIdx.y;          // 0..7, two batches each
    const int t  = threadIdx.x;
    float amax = 0.f, wmax = 0.f;
    for (int bb = 2 * bq; bb < 2 * bq + 2; ++bb) {
        const float* xp = x + ((size_t)(bb * IC + ic)) * (IH * IW);
        for (int hw = t * 4; hw < IH * IW; hw += 1024) {
            float4 v = *(const float4*)(xp + hw);
            amax = fmaxf(amax, fmaxf(fmaxf(fabsf(v.x), fabsf(v.y)),
                                     fmaxf(fabsf(v.z), fabsf(v.w))));
        }
    }
    if (bq == 0)
        for (int j = t; j < OCH * 9; j += 256)
            wmax = fmaxf(wmax, fabsf(w[ic * (OCH * 9) + j]));
    __shared__ float r1[256], r2[256];
    r1[t] = wmax; r2[t] = amax;
    __syncthreads();
    for (int s = 128; s > 0; s >>= 1) {
        if (t < s) {
            r1[t] = fmaxf(r1[t], r1[t + s]);
            r2[t] = fmaxf(r2[t], r2[t + s]);
        }
        __syncthreads();
    }
    if (t == 0) {
        ws[WS_APART + bq * 256 + ic] = r2[0];
        if (bq == 0) ws[WS_WSCALE + ic] = r1[0];
    }
}

// ---- K2 (fused): scale finalize (redundant per block) + w-quant + x-quant ----
// blocks 0..287: wq8[tap][kq(16)][oc(128)][16B]
// blocks 288..1311: qx[b][row][v][ic ^ swz] (r19 linear mapping — r20's
//   XCD-aligned variant regressed; qx locality is not on the critical path)
__global__ __launch_bounds__(256) void k_quant(
        const float* __restrict__ x, const float* __restrict__ w,
        float* __restrict__ ws) {
    __shared__ float scs[256], sqs[256], r1[256], r2[256];
    __shared__ unsigned tmp[4096];      // x-path transpose buffer (16 KB)
    const int t = threadIdx.x;          // = ic for the scale phase
    float asc = 0.f;
    #pragma unroll
    for (int q8 = 0; q8 < 8; ++q8) asc = fmaxf(asc, ws[WS_APART + q8 * 256 + t]);
    const float wsc = ws[WS_WSCALE + t];
    float sc = sqrtf(asc) / sqrtf(wsc);
    if (sc == 0.f) sc = 1.f;
    r1[t] = wsc * sc;                   // elementwise max of |w*sc| (monotone)
    r2[t] = asc / sc;                   // elementwise max of |x/sc|
    __syncthreads();
    for (int s = 128; s > 0; s >>= 1) {
        if (t < s) {
            r1[t] = fmaxf(r1[t], r1[t + s]);
            r2[t] = fmaxf(r2[t], r2[t + s]);
        }
        __syncthreads();
    }
    float sw = r1[0] / QMAXF; if (sw == 0.f) sw = 1.f;
    float sx = r2[0] / QMAXF; if (sx == 0.f) sx = 1.f;
    scs[t] = sc / sw;                   // weight multiplier
    sqs[t] = 1.f / (sc * sx);           // activation multiplier
    if (blockIdx.x == 0 && t == 0) ws[WS_F] = sx * sw;
    __syncthreads();

    if (blockIdx.x < 288) {
        // ---- weight quant path ----
        const int idx = blockIdx.x * 256 + t;   // [tap][kq][oc][e4]
        const int e0  = (idx & 3) * 4;
        const int oc  = (idx >> 2) & 127;
        const int kq  = (idx >> 9) & 15;
        const int tap = idx >> 13;
        unsigned pack = 0;
        #pragma unroll
        for (int c = 0; c < 4; ++c) {
            const int ic = kq * 16 + e0 + c;
            float q = rintf(w[((size_t)ic * OCH + oc) * 9 + tap] * scs[ic]);
            q = fminf(fmaxf(q, -128.f), 127.f);
            pack |= ((unsigned)((int)q & 255)) << (8 * c);
        }
        ((unsigned*)(ws + WS_WQ8))[idx] = pack;
    } else {
        // ---- activation quant + transpose path ----
        const int bid = blockIdx.x - 288;
        const int row = bid & 63;
        const int b   = bid >> 6;
        const int v   = t & 63;         // lane <-> column, coalesced x reads
        for (int j = t; j < 4096; j += 256) {
            const int ic0 = ((j >> 6) & 63) * 4;
            const float* xp = x + (((size_t)(b * IC + ic0)) * IH + row) * IW + v;
            unsigned pack = 0;
            #pragma unroll
            for (int c = 0; c < 4; ++c) {
                float qv = fminf(fmaxf(rintf(xp[(size_t)c * IH * IW] * sqs[ic0 + c]),
                                       -128.f), 127.f);
                pack |= ((unsigned)((int)qv & 255)) << (8 * c);
            }
            tmp[v * 64 + (((unsigned)ic0 >> 2) ^ (((unsigned)(v & 15)) << 2))] = pack;
        }
        __syncthreads();
        // coalesced 16 KB writeback (stays in L2/L3 for k_conv)
        i32x4* dst = (i32x4*)((char*)(ws + WS_QX) + (((size_t)b * IH + row) * 64) * 256);
        const i32x4* src = (const i32x4*)tmp;
        #pragma unroll
        for (int i = 0; i < 4; ++i)
            dst[i * 256 + t] = src[i * 256 + t];
    }
}

// ------- K3: MFMA conv, 16x16x64, 4-wave blocks, FUSED row phases -------
// A-tile int8 [r(2)][v(66)][ic(256)], byte = (r*66+v)*256 + (ic ^ ((v&15)<<4))
// 4 distinct A-classes (R,S): (0,0)={4,5,7,8} (0,1)={3,6} (1,0)={1,2} (1,1)={0}.
// Fusing both output rows shares ALL classes across all 9 taps: 64 ds_reads/wave
// (vs 96 in r19). vt split into halves keeps acc at 32 regs (no spill cliff).
__device__ __forceinline__ i32x4 load_a16(const char* qa, int R, int S, int kstep,
                                          int vt, int lane) {
    const int v = vt * 16 + (lane & 15) + S;
    const unsigned byte = (unsigned)((R * 66 + v) * 256)
        + ((((unsigned)(kstep * 4 + (lane >> 4))) << 4) ^ (((unsigned)(v & 15)) << 4));
    return *(const i32x4*)(qa + byte);
}

__device__ __forceinline__ i32x4 load_b16(const char* wq8, int tap, int kstep,
                                          int oc0, int lane) {
    const size_t off = ((size_t)((tap * 16 + kstep * 4 + (lane >> 4)) * OCH
                                 + oc0 + (lane & 15))) * 16;
    return *(const i32x4*)(wq8 + off);
}

#define MFMA16(B, A, ACC) \
    ACC = __builtin_amdgcn_mfma_i32_16x16x64_i8(B, A, ACC, 0, 0, 0)

__global__ __launch_bounds__(256) void k_conv(
        const float* __restrict__ bias,
        const float* __restrict__ ws, float* __restrict__ out) {
    __shared__ __align__(16) char qa[33792];

    const int tid  = threadIdx.x;
    // bijective XCD swizzle (2048 % 8 == 0); f0 = b*128 + u*2 + half
    const int f0   = (blockIdx.x & 7) * 256 + (blockIdx.x >> 3);
    const int half = f0 & 1;         // oc half: 0 -> oc 0..63, 1 -> 64..127
    const int u    = (f0 >> 1) & 63; // output rows 2u, 2u+1
    const int b    = f0 >> 7;
    const int lane = tid & 63;
    const int wid  = tid >> 6;       // 0..3, wave = 16-oc slice within the half
    const int oc0  = half * 64 + wid * 16;

    if (tid < 32) {                  // zero pad column v=64 (both r)
        const int r = tid >> 4;
        *(i32x4*)(qa + (r * 66 + 64) * 256 + (tid & 15) * 16) = (i32x4)(0);
    }

    // staging = pure linear copy of pre-quantized, pre-swizzled rows (16 KB each)
    const char* qx = (const char*)(ws + WS_QX);
    #pragma unroll
    for (int r = 0; r < 2; ++r) {
        const int row = u + r;
        i32x4* dst = (i32x4*)(qa + r * 66 * 256);
        if (row < IH) {
            const i32x4* src = (const i32x4*)(qx + (((size_t)b * IH + row) * 64) * 256);
            #pragma unroll
            for (int i = 0; i < 4; ++i)
                dst[i * 256 + tid] = src[i * 256 + tid];
        } else {
            #pragma unroll
            for (int i = 0; i < 4; ++i)
                dst[i * 256 + tid] = (i32x4)(0);
        }
    }
    __syncthreads();                 // the ONLY barrier

    const char* wq8 = (const char*)(ws + WS_WQ8);
    const float fsc = ws[WS_F];
    const int ocq = oc0 + 4 * (lane >> 4);   // D: row = oc = ocq + reg

    // bias for this lane's 4 oc rows (L2-cached global reads, loaded once)
    float bv[4];
    #pragma unroll
    for (int reg = 0; reg < 4; ++reg) bv[reg] = bias[ocq + reg];

    // two vt-halves: acc = 4 sets x 2 vt x i32x4 = 32 regs per half
    #pragma unroll
    for (int hf = 0; hf < 2; ++hf) {
        i32x4 aP0r0[2], aP1r0[2], aP0r1[2], aP1r1[2];
        #pragma unroll
        for (int i = 0; i < 2; ++i) {
            aP0r0[i] = (i32x4)(0); aP1r0[i] = (i32x4)(0);
            aP0r1[i] = (i32x4)(0); aP1r1[i] = (i32x4)(0);
        }
        #pragma unroll
        for (int k = 0; k < 4; ++k) {
            const i32x4 b0 = load_b16(wq8, 0, k, oc0, lane);
            const i32x4 b1 = load_b16(wq8, 1, k, oc0, lane);
            const i32x4 b2 = load_b16(wq8, 2, k, oc0, lane);
            const i32x4 b3 = load_b16(wq8, 3, k, oc0, lane);
            const i32x4 b4 = load_b16(wq8, 4, k, oc0, lane);
            const i32x4 b5 = load_b16(wq8, 5, k, oc0, lane);
            const i32x4 b6 = load_b16(wq8, 6, k, oc0, lane);
            const i32x4 b7 = load_b16(wq8, 7, k, oc0, lane);
            const i32x4 b8 = load_b16(wq8, 8, k, oc0, lane);
            #pragma unroll
            for (int v2 = 0; v2 < 2; ++v2) {
                const int vt = 2 * hf + v2;
                const i32x4 a00 = load_a16(qa, 0, 0, k, vt, lane);
                const i32x4 a01 = load_a16(qa, 0, 1, k, vt, lane);
                const i32x4 a10 = load_a16(qa, 1, 0, k, vt, lane);
                const i32x4 a11 = load_a16(qa, 1, 1, k, vt, lane);
                // row 2u:   par0 {4}@a00;      par1 {3}@a01 + {5}@a00
                MFMA16(b4, a00, aP0r0[v2]);
                MFMA16(b3, a01, aP1r0[v2]);
                MFMA16(b5, a00, aP1r0[v2]);
                // row 2u+1: par0 {1}@a10+{7}@a00; par1 {0}@a11+{2}@a10+{6}@a01+{8}@a00
                MFMA16(b1, a10, aP0r1[v2]);
                MFMA16(b7, a00, aP0r1[v2]);
                MFMA16(b0, a11, aP1r1[v2]);
                MFMA16(b2, a10, aP1r1[v2]);
                MFMA16(b6, a01, aP1r1[v2]);
                MFMA16(b8, a00, aP1r1[v2]);
            }
        }
        // dense f32x2 NT stores for this half (both rows, vt in {2hf, 2hf+1})
        #pragma unroll
        for (int reg = 0; reg < 4; ++reg) {
            float* r0p = out + (((size_t)(b * OCH + ocq + reg)) * OH2 + 2 * u) * OW2;
            #pragma unroll
            for (int v2 = 0; v2 < 2; ++v2) {
                const int v = (2 * hf + v2) * 16 + (lane & 15);
                f32x2 o0, o1;
                o0.x = fmaf((float)aP0r0[v2][reg], fsc, bv[reg]);
                o0.y = fmaf((float)aP1r0[v2][reg], fsc, bv[reg]);
                o1.x = fmaf((float)aP0r1[v2][reg], fsc, bv[reg]);
                o1.y = fmaf((float)aP1r1[v2][reg], fsc, bv[reg]);
                __builtin_nontemporal_store(o0, (f32x2*)(r0p + 2 * v));
                __builtin_nontemporal_store(o1, (f32x2*)(r0p + OW2 + 2 * v));
            }
        }
    }
}

extern "C" void kernel_launch(void* const* d_in, const int* in_sizes, int n_in,
                              void* d_out, int out_size, void* d_ws, size_t ws_size,
                              hipStream_t stream) {
    const float* x    = (const float*)d_in[0];
    const float* w    = (const float*)d_in[1];
    const float* bias = (const float*)d_in[2];
    float* ws  = (float*)d_ws;
    float* out = (float*)d_out;

    k_channel_scales<<<dim3(256, 8), 256, 0, stream>>>(x, w, ws);
    k_quant<<<1312, 256, 0, stream>>>(x, w, ws);
    k_conv<<<2048, 256, 0, stream>>>(bias, ws, out);
}

// Round 22
// 61.674 us; speedup vs baseline: 1.1008x; 1.1008x over previous
//
#include <hip/hip_runtime.h>

typedef __attribute__((ext_vector_type(4))) int  i32x4;
typedef __attribute__((ext_vector_type(2))) float f32x2;

#define IC   256
#define OCH  128
#define BSZ  16
#define IH   64
#define IW   64
#define OH2  128
#define OW2  128
#define QMAXF 127.0f

// ws float-offset layout
#define WS_WSCALE 0        // 256 per-ic weight absmax
#define WS_APART  256      // 8*256 per-(bq,ic) act absmax partials
#define WS_F      2816     // sx*sw
#define WS_WQ8    3072     // int8 [9][16][128][16] quantized weights (294912 B)
#define WS_QX     76800    // int8 [16][64][64][256] pre-swizzled quantized x (16.78 MB)

// ---------------- K1: per-channel absmax (partials over batch) ----------------
__global__ __launch_bounds__(256) void k_channel_scales(
        const float* __restrict__ x, const float* __restrict__ w,
        float* __restrict__ ws) {
    const int ic = blockIdx.x;
    const int bq = blockIdx.y;          // 0..7, two batches each
    const int t  = threadIdx.x;
    float amax = 0.f, wmax = 0.f;
    for (int bb = 2 * bq; bb < 2 * bq + 2; ++bb) {
        const float* xp = x + ((size_t)(bb * IC + ic)) * (IH * IW);
        for (int hw = t * 4; hw < IH * IW; hw += 1024) {
            float4 v = *(const float4*)(xp + hw);
            amax = fmaxf(amax, fmaxf(fmaxf(fabsf(v.x), fabsf(v.y)),
                                     fmaxf(fabsf(v.z), fabsf(v.w))));
        }
    }
    if (bq == 0)
        for (int j = t; j < OCH * 9; j += 256)
            wmax = fmaxf(wmax, fabsf(w[ic * (OCH * 9) + j]));
    __shared__ float r1[256], r2[256];
    r1[t] = wmax; r2[t] = amax;
    __syncthreads();
    for (int s = 128; s > 0; s >>= 1) {
        if (t < s) {
            r1[t] = fmaxf(r1[t], r1[t + s]);
            r2[t] = fmaxf(r2[t], r2[t + s]);
        }
        __syncthreads();
    }
    if (t == 0) {
        ws[WS_APART + bq * 256 + ic] = r2[0];
        if (bq == 0) ws[WS_WSCALE + ic] = r1[0];
    }
}

// ---- K2 (fused): scale finalize (redundant per block) + w-quant + x-quant ----
// blocks 0..287: wq8[tap][kq(16)][oc(128)][16B]
// blocks 288..1311: qx[b][row][v][ic ^ swz] (pre-swizzled for linear LDS staging)
__global__ __launch_bounds__(256) void k_quant(
        const float* __restrict__ x, const float* __restrict__ w,
        float* __restrict__ ws) {
    __shared__ float scs[256], sqs[256], r1[256], r2[256];
    __shared__ unsigned tmp[4096];      // x-path transpose buffer (16 KB)
    const int t = threadIdx.x;          // = ic for the scale phase
    float asc = 0.f;
    #pragma unroll
    for (int q8 = 0; q8 < 8; ++q8) asc = fmaxf(asc, ws[WS_APART + q8 * 256 + t]);
    const float wsc = ws[WS_WSCALE + t];
    float sc = sqrtf(asc) / sqrtf(wsc);
    if (sc == 0.f) sc = 1.f;
    r1[t] = wsc * sc;                   // elementwise max of |w*sc| (monotone)
    r2[t] = asc / sc;                   // elementwise max of |x/sc|
    __syncthreads();
    for (int s = 128; s > 0; s >>= 1) {
        if (t < s) {
            r1[t] = fmaxf(r1[t], r1[t + s]);
            r2[t] = fmaxf(r2[t], r2[t + s]);
        }
        __syncthreads();
    }
    float sw = r1[0] / QMAXF; if (sw == 0.f) sw = 1.f;
    float sx = r2[0] / QMAXF; if (sx == 0.f) sx = 1.f;
    scs[t] = sc / sw;                   // weight multiplier
    sqs[t] = 1.f / (sc * sx);           // activation multiplier
    if (blockIdx.x == 0 && t == 0) ws[WS_F] = sx * sw;
    __syncthreads();

    if (blockIdx.x < 288) {
        // ---- weight quant path ----
        const int idx = blockIdx.x * 256 + t;   // [tap][kq][oc][e4]
        const int e0  = (idx & 3) * 4;
        const int oc  = (idx >> 2) & 127;
        const int kq  = (idx >> 9) & 15;
        const int tap = idx >> 13;
        unsigned pack = 0;
        #pragma unroll
        for (int c = 0; c < 4; ++c) {
            const int ic = kq * 16 + e0 + c;
            float q = rintf(w[((size_t)ic * OCH + oc) * 9 + tap] * scs[ic]);
            q = fminf(fmaxf(q, -128.f), 127.f);
            pack |= ((unsigned)((int)q & 255)) << (8 * c);
        }
        ((unsigned*)(ws + WS_WQ8))[idx] = pack;
    } else {
        // ---- activation quant + transpose path ----
        const int bid = blockIdx.x - 288;
        const int row = bid & 63;
        const int b   = bid >> 6;
        const int v   = t & 63;         // lane <-> column, coalesced x reads
        for (int j = t; j < 4096; j += 256) {
            const int ic0 = ((j >> 6) & 63) * 4;
            const float* xp = x + (((size_t)(b * IC + ic0)) * IH + row) * IW + v;
            unsigned pack = 0;
            #pragma unroll
            for (int c = 0; c < 4; ++c) {
                float qv = fminf(fmaxf(rintf(xp[(size_t)c * IH * IW] * sqs[ic0 + c]),
                                       -128.f), 127.f);
                pack |= ((unsigned)((int)qv & 255)) << (8 * c);
            }
            tmp[v * 64 + (((unsigned)ic0 >> 2) ^ (((unsigned)(v & 15)) << 2))] = pack;
        }
        __syncthreads();
        // coalesced 16 KB writeback (stays in L2/L3 for k_conv)
        i32x4* dst = (i32x4*)((char*)(ws + WS_QX) + (((size_t)b * IH + row) * 64) * 256);
        const i32x4* src = (const i32x4*)tmp;
        #pragma unroll
        for (int i = 0; i < 4; ++i)
            dst[i * 256 + t] = src[i * 256 + t];
    }
}

// ------- K3: MFMA conv, 16x16x64, 4-wave blocks (wave = 16-oc slice) -------
// A-tile int8 [r(2)][v(66)][ic(256)], byte = (r*66+v)*256 + (ic ^ ((v&15)<<4))
// Taps collapse to 4 distinct A-fragment classes (R,S):
//   (0,0)={4,5,7,8}  (0,1)={3,6}  (1,0)={1,2}  (1,1)={0}
// -> share A-loads across taps within each row phase (144 -> 96 ds_reads/wave).
__device__ __forceinline__ i32x4 load_a16(const char* qa, int R, int S, int kstep,
                                          int vt, int lane) {
    const int v = vt * 16 + (lane & 15) + S;
    const unsigned byte = (unsigned)((R * 66 + v) * 256)
        + ((((unsigned)(kstep * 4 + (lane >> 4))) << 4) ^ (((unsigned)(v & 15)) << 4));
    return *(const i32x4*)(qa + byte);
}

__device__ __forceinline__ i32x4 load_b16(const char* wq8, int tap, int kstep,
                                          int oc0, int lane) {
    const size_t off = ((size_t)((tap * 16 + kstep * 4 + (lane >> 4)) * OCH
                                 + oc0 + (lane & 15))) * 16;
    return *(const i32x4*)(wq8 + off);
}

#define MFMA16(B, A, ACC) \
    ACC = __builtin_amdgcn_mfma_i32_16x16x64_i8(B, A, ACC, 0, 0, 0)

// row 2u: par0 {tap4}@a00, par1 {tap3}@a01 + {tap5}@a00
__device__ __forceinline__ void row0_phase(const char* qa, const char* wq8,
        int oc0, int lane, i32x4 (&p0)[4], i32x4 (&p1)[4]) {
    #pragma unroll
    for (int k = 0; k < 4; ++k) {
        const i32x4 b4 = load_b16(wq8, 4, k, oc0, lane);
        const i32x4 b3 = load_b16(wq8, 3, k, oc0, lane);
        const i32x4 b5 = load_b16(wq8, 5, k, oc0, lane);
        #pragma unroll
        for (int vt = 0; vt < 4; ++vt) {
            const i32x4 a00 = load_a16(qa, 0, 0, k, vt, lane);
            const i32x4 a01 = load_a16(qa, 0, 1, k, vt, lane);
            MFMA16(b4, a00, p0[vt]);
            MFMA16(b3, a01, p1[vt]);
            MFMA16(b5, a00, p1[vt]);
        }
    }
}

// row 2u+1: par0 {tap1}@a10 + {tap7}@a00, par1 {0}@a11 + {2}@a10 + {6}@a01 + {8}@a00
__device__ __forceinline__ void row1_phase(const char* qa, const char* wq8,
        int oc0, int lane, i32x4 (&p0)[4], i32x4 (&p1)[4]) {
    #pragma unroll
    for (int k = 0; k < 4; ++k) {
        const i32x4 b1 = load_b16(wq8, 1, k, oc0, lane);
        const i32x4 b7 = load_b16(wq8, 7, k, oc0, lane);
        const i32x4 b0 = load_b16(wq8, 0, k, oc0, lane);
        const i32x4 b2 = load_b16(wq8, 2, k, oc0, lane);
        const i32x4 b6 = load_b16(wq8, 6, k, oc0, lane);
        const i32x4 b8 = load_b16(wq8, 8, k, oc0, lane);
        #pragma unroll
        for (int vt = 0; vt < 4; ++vt) {
            const i32x4 a00 = load_a16(qa, 0, 0, k, vt, lane);
            const i32x4 a01 = load_a16(qa, 0, 1, k, vt, lane);
            const i32x4 a10 = load_a16(qa, 1, 0, k, vt, lane);
            const i32x4 a11 = load_a16(qa, 1, 1, k, vt, lane);
            MFMA16(b1, a10, p0[vt]);
            MFMA16(b7, a00, p0[vt]);
            MFMA16(b0, a11, p1[vt]);
            MFMA16(b2, a10, p1[vt]);
            MFMA16(b6, a01, p1[vt]);
            MFMA16(b8, a00, p1[vt]);
        }
    }
}

__global__ __launch_bounds__(256) void k_conv(
        const float* __restrict__ bias,
        const float* __restrict__ ws, float* __restrict__ out) {
    __shared__ __align__(16) char qa[33792];

    const int tid  = threadIdx.x;
    // bijective XCD swizzle (2048 % 8 == 0); f0 = b*128 + u*2 + half, so the
    // two oc-half blocks of a row-pair land on the SAME XCD (shared qx rows).
    const int f0   = (blockIdx.x & 7) * 256 + (blockIdx.x >> 3);
    const int half = f0 & 1;         // oc half: 0 -> oc 0..63, 1 -> 64..127
    const int u    = (f0 >> 1) & 63; // output rows 2u, 2u+1
    const int b    = f0 >> 7;
    const int lane = tid & 63;
    const int wid  = tid >> 6;       // 0..3, wave = 16-oc slice within the half
    const int oc0  = half * 64 + wid * 16;

    if (tid < 32) {                  // zero pad column v=64 (both r)
        const int r = tid >> 4;
        *(i32x4*)(qa + (r * 66 + 64) * 256 + (tid & 15) * 16) = (i32x4)(0);
    }

    // staging = pure linear copy of pre-quantized, pre-swizzled rows (16 KB each)
    const char* qx = (const char*)(ws + WS_QX);
    #pragma unroll
    for (int r = 0; r < 2; ++r) {
        const int row = u + r;
        i32x4* dst = (i32x4*)(qa + r * 66 * 256);
        if (row < IH) {
            const i32x4* src = (const i32x4*)(qx + (((size_t)b * IH + row) * 64) * 256);
            #pragma unroll
            for (int i = 0; i < 4; ++i)
                dst[i * 256 + tid] = src[i * 256 + tid];
        } else {
            #pragma unroll
            for (int i = 0; i < 4; ++i)
                dst[i * 256 + tid] = (i32x4)(0);
        }
    }
    __syncthreads();                 // the ONLY barrier

    const char* wq8 = (const char*)(ws + WS_WQ8);
    const float fsc = ws[WS_F];
    const int ocq = oc0 + 4 * (lane >> 4);   // D: row = oc = ocq + reg

    // bias for this lane's 4 oc rows (L2-cached global reads, loaded once)
    float bv[4];
    #pragma unroll
    for (int reg = 0; reg < 4; ++reg) bv[reg] = bias[ocq + reg];

    // dense f32x2 NT stores: col=lane&15 = v-within-tile, both parities in-lane
    auto store_row = [&](const i32x4 (&p0)[4], const i32x4 (&p1)[4], int oh) {
        #pragma unroll
        for (int reg = 0; reg < 4; ++reg) {
            float* rowp = out + (((size_t)(b * OCH + ocq + reg)) * OH2 + oh) * OW2;
            #pragma unroll
            for (int vt = 0; vt < 4; ++vt) {
                f32x2 o;
                o.x = fmaf((float)p0[vt][reg], fsc, bv[reg]);
                o.y = fmaf((float)p1[vt][reg], fsc, bv[reg]);
                __builtin_nontemporal_store(o,
                    (f32x2*)(rowp + 2 * (vt * 16 + (lane & 15))));
            }
        }
    };

    i32x4 accP0[4], accP1[4];        // 32 VGPR accumulator total

    // ---- output row 2u ----
    #pragma unroll
    for (int i = 0; i < 4; ++i) { accP0[i] = (i32x4)(0); accP1[i] = (i32x4)(0); }
    row0_phase(qa, wq8, oc0, lane, accP0, accP1);
    store_row(accP0, accP1, 2 * u);

    // ---- output row 2u+1 ----
    #pragma unroll
    for (int i = 0; i < 4; ++i) { accP0[i] = (i32x4)(0); accP1[i] = (i32x4)(0); }
    row1_phase(qa, wq8, oc0, lane, accP0, accP1);
    store_row(accP0, accP1, 2 * u + 1);
}

extern "C" void kernel_launch(void* const* d_in, const int* in_sizes, int n_in,
                              void* d_out, int out_size, void* d_ws, size_t ws_size,
                              hipStream_t stream) {
    const float* x    = (const float*)d_in[0];
    const float* w    = (const float*)d_in[1];
    const float* bias = (const float*)d_in[2];
    float* ws  = (float*)d_ws;
    float* out = (float*)d_out;

    k_channel_scales<<<dim3(256, 8), 256, 0, stream>>>(x, w, ws);
    k_quant<<<1312, 256, 0, stream>>>(x, w, ws);
    k_conv<<<2048, 256, 0, stream>>>(bias, ws, out);
}